// Round 4
// baseline (912.803 us; speedup 1.0000x reference)
//
#include <hip/hip_runtime.h>
#include <hip/hip_bf16.h>

#define NN 50000
#define EE 400000
#define PP 3
#define NBLK 196   // ceil(NN/256)
// H=4, D=32, IN=128, HD=128

__device__ __forceinline__ float eluf(float v) {
    return v > 0.f ? v : (expf(v) - 1.f);
}

__device__ __forceinline__ void fma4(float4& a, float s, const float4& w) {
    a.x += s * w.x; a.y += s * w.y; a.z += s * w.z; a.w += s * w.w;
}

__device__ __forceinline__ unsigned short f2bf(float f) {
    unsigned int u = __float_as_uint(f);
    u = (u + 0x7FFFu + ((u >> 16) & 1u)) >> 16;
    return (unsigned short)u;
}

// ---------------- K1a: w[n,r] = tanh(C[n,r,:]@W1 + b1)@w2 ----------------
// one thread per 4 rows (node chunk q: rows 4q..4q+3); 250k threads
__global__ __launch_bounds__(256) void k_fa_w(
    const float* __restrict__ c, const float* __restrict__ w1,
    const float* __restrict__ b1, const float* __restrict__ w2,
    float* __restrict__ wout)
{
    __shared__ float sW1[42 * 16];
    const int tid = threadIdx.x;
    for (int i = tid; i < 672; i += 256) sW1[i] = w1[i];
    __syncthreads();

    const int t = blockIdx.x * 256 + tid;
    if (t >= NN * 5) return;
    const int n = t / 5;
    const int q = t - 5 * n;

    const float2* base = (const float2*)(c + (size_t)n * 840 + q * 168);
    const float4* sW4 = (const float4*)sW1;

    float4 acc[4][4];
    #pragma unroll
    for (int r = 0; r < 4; ++r)
        #pragma unroll
        for (int jq = 0; jq < 4; ++jq) acc[r][jq] = make_float4(0.f, 0.f, 0.f, 0.f);

    #pragma unroll 3
    for (int i2 = 0; i2 < 21; ++i2) {
        const float4 wa0 = sW4[(2 * i2) * 4 + 0];
        const float4 wa1 = sW4[(2 * i2) * 4 + 1];
        const float4 wa2 = sW4[(2 * i2) * 4 + 2];
        const float4 wa3 = sW4[(2 * i2) * 4 + 3];
        const float4 wb0 = sW4[(2 * i2 + 1) * 4 + 0];
        const float4 wb1 = sW4[(2 * i2 + 1) * 4 + 1];
        const float4 wb2 = sW4[(2 * i2 + 1) * 4 + 2];
        const float4 wb3 = sW4[(2 * i2 + 1) * 4 + 3];
        #pragma unroll
        for (int r = 0; r < 4; ++r) {
            const float2 v = base[r * 21 + i2];
            fma4(acc[r][0], v.x, wa0); fma4(acc[r][1], v.x, wa1);
            fma4(acc[r][2], v.x, wa2); fma4(acc[r][3], v.x, wa3);
            fma4(acc[r][0], v.y, wb0); fma4(acc[r][1], v.y, wb1);
            fma4(acc[r][2], v.y, wb2); fma4(acc[r][3], v.y, wb3);
        }
    }

    float4 bb[4], ww[4];
    #pragma unroll
    for (int jq = 0; jq < 4; ++jq) {
        bb[jq] = ((const float4*)b1)[jq];
        ww[jq] = ((const float4*)w2)[jq];
    }
    float* wo = wout + (size_t)n * 20 + q * 4;
    #pragma unroll
    for (int r = 0; r < 4; ++r) {
        float s = 0.f;
        #pragma unroll
        for (int jq = 0; jq < 4; ++jq) {
            s += tanhf(acc[r][jq].x + bb[jq].x) * ww[jq].x;
            s += tanhf(acc[r][jq].y + bb[jq].y) * ww[jq].y;
            s += tanhf(acc[r][jq].z + bb[jq].z) * ww[jq].z;
            s += tanhf(acc[r][jq].w + bb[jq].w) * ww[jq].w;
        }
        wo[r] = s;
    }
}

// ---------------- K1b: softmax(w) weighted sum + concat h -> x ----------
// one wave per node; 4 nodes per block
__global__ __launch_bounds__(256) void k_fa_emb(
    const float* __restrict__ h, const float* __restrict__ c,
    const float* __restrict__ w, float* __restrict__ x)
{
    const int wid = threadIdx.x >> 6, lane = threadIdx.x & 63;
    const int n = blockIdx.x * 4 + wid;
    if (n >= NN) return;

    const float* wn = w + (size_t)n * 20;
    float wv[20];
    #pragma unroll
    for (int r = 0; r < 20; ++r) wv[r] = wn[r];
    float m = wv[0];
    #pragma unroll
    for (int r = 1; r < 20; ++r) m = fmaxf(m, wv[r]);
    float s = 0.f;
    #pragma unroll
    for (int r = 0; r < 20; ++r) { wv[r] = expf(wv[r] - m); s += wv[r]; }
    const float inv = 1.f / s;

    if (lane < 42) {
        const float* cn = c + (size_t)n * 840;
        float acc = 0.f;
        #pragma unroll
        for (int r = 0; r < 20; ++r) acc += wv[r] * cn[r * 42 + lane];
        x[(size_t)n * 128 + 86 + lane] = acc * inv;
    }
    x[(size_t)n * 128 + lane] = h[(size_t)n * 86 + lane];
    if (lane < 22)
        x[(size_t)n * 128 + 64 + lane] = h[(size_t)n * 86 + 64 + lane];
}

// ---------------- K2: feat(bf16) = x @ W_p, plus el/er epilogue ----------
__global__ __launch_bounds__(256) void k_gat_gemm(
    const float* __restrict__ x, const float* __restrict__ W,
    const float* __restrict__ attn_l, const float* __restrict__ attn_r,
    unsigned short* __restrict__ featb, float* __restrict__ el, float* __restrict__ er)
{
    __shared__ float sX[64 * 128];
    const int tid = threadIdx.x;
    const int p  = blockIdx.y;
    const int n0 = blockIdx.x * 64;

    float4* sX4 = (float4*)sX;
    for (int i = tid; i < 2048; i += 256) {
        const int row = i >> 5, c4 = i & 31;
        float4 v = make_float4(0.f, 0.f, 0.f, 0.f);
        if (n0 + row < NN) v = ((const float4*)(x + (size_t)(n0 + row) * 128))[c4];
        sX4[i] = v;
    }
    __syncthreads();

    const int tc = tid & 31;   // 4-col group
    const int tr = tid >> 5;   // 8-row group
    const float4* Wp4 = (const float4*)(W + (size_t)p * 128 * 128);

    float4 acc[8];
    #pragma unroll
    for (int r = 0; r < 8; ++r) acc[r] = make_float4(0.f, 0.f, 0.f, 0.f);

    for (int kq = 0; kq < 32; ++kq) {
        const float4 wv0 = Wp4[(4 * kq + 0) * 32 + tc];
        const float4 wv1 = Wp4[(4 * kq + 1) * 32 + tc];
        const float4 wv2 = Wp4[(4 * kq + 2) * 32 + tc];
        const float4 wv3 = Wp4[(4 * kq + 3) * 32 + tc];
        #pragma unroll
        for (int r = 0; r < 8; ++r) {
            const float4 xv = sX4[(tr * 8 + r) * 32 + kq];
            fma4(acc[r], xv.x, wv0);
            fma4(acc[r], xv.y, wv1);
            fma4(acc[r], xv.z, wv2);
            fma4(acc[r], xv.w, wv3);
        }
    }

    float4 al, ar;
    {
        al = ((const float4*)(attn_l + p * 128))[tc];
        ar = ((const float4*)(attn_r + p * 128))[tc];
    }
    const int hh = tc >> 3;
    for (int r = 0; r < 8; ++r) {
        const int n = n0 + tr * 8 + r;
        const bool ok = n < NN;
        if (ok) {
            ushort4 sv;
            sv.x = f2bf(acc[r].x); sv.y = f2bf(acc[r].y);
            sv.z = f2bf(acc[r].z); sv.w = f2bf(acc[r].w);
            ((ushort4*)(featb + (size_t)(p * NN + n) * 128))[tc] = sv;
        }
        float pl = acc[r].x*al.x + acc[r].y*al.y + acc[r].z*al.z + acc[r].w*al.w;
        float pr = acc[r].x*ar.x + acc[r].y*ar.y + acc[r].z*ar.z + acc[r].w*ar.w;
        pl += __shfl_xor(pl, 1); pl += __shfl_xor(pl, 2); pl += __shfl_xor(pl, 4);
        pr += __shfl_xor(pr, 1); pr += __shfl_xor(pr, 2); pr += __shfl_xor(pr, 4);
        if (ok && (tc & 7) == 0) {
            el[(size_t)(p * NN + n) * 4 + hh] = pl;
            er[(size_t)(p * NN + n) * 4 + hh] = pr;
        }
    }
}

// ---------------- CSR build: histogram ----------------
__global__ __launch_bounds__(256) void k_hist(
    const int* __restrict__ dst, int* __restrict__ deg)
{
    const int p = blockIdx.y;
    const int e = blockIdx.x * 256 + threadIdx.x;
    if (e < EE) atomicAdd(&deg[p * NN + dst[p * EE + e]], 1);
}

// ---------------- CSR build: per-block partial sums ----------------
__global__ __launch_bounds__(256) void k_partial(
    const int* __restrict__ deg, int* __restrict__ psum)
{
    __shared__ int s[256];
    const int p = blockIdx.y;
    const int i = blockIdx.x * 256 + threadIdx.x;
    s[threadIdx.x] = (i < NN) ? deg[p * NN + i] : 0;
    __syncthreads();
    for (int off = 128; off > 0; off >>= 1) {
        if (threadIdx.x < off) s[threadIdx.x] += s[threadIdx.x + off];
        __syncthreads();
    }
    if (threadIdx.x == 0) psum[p * NBLK + blockIdx.x] = s[0];
}

// ---------------- CSR build: scan block partials (tiny) ----------------
__global__ void k_scanpsum(int* __restrict__ psum)
{
    const int p = blockIdx.x;
    if (threadIdx.x == 0) {
        int run = 0;
        for (int i = 0; i < NBLK; ++i) {
            int t = psum[p * NBLK + i];
            psum[p * NBLK + i] = run;
            run += t;
        }
    }
}

// ---------------- CSR build: final exclusive scan -> row_start, cursor ----
__global__ __launch_bounds__(256) void k_scanfinal(
    const int* __restrict__ deg, const int* __restrict__ psum,
    int* __restrict__ row_start, int* __restrict__ cursor)
{
    __shared__ int s[256];
    const int p = blockIdx.y, t = threadIdx.x;
    const int i = blockIdx.x * 256 + t;
    const int v = (i < NN) ? deg[p * NN + i] : 0;
    s[t] = v;
    __syncthreads();
    for (int off = 1; off < 256; off <<= 1) {
        int xv = 0;
        if (t >= off) xv = s[t - off];
        __syncthreads();
        s[t] += xv;
        __syncthreads();
    }
    const int excl = s[t] - v + psum[p * NBLK + blockIdx.x];
    if (i < NN) {
        row_start[p * (NN + 1) + i] = excl;
        cursor[p * NN + i] = excl;
        if (i == NN - 1) row_start[p * (NN + 1) + NN] = excl + v;
    }
}

// ---------------- scatter: sorted src + per-edge exp(leaky(el+er)) -------
__global__ __launch_bounds__(256) void k_scatter(
    const int* __restrict__ src, const int* __restrict__ dst,
    const float* __restrict__ el, const float* __restrict__ er,
    int* __restrict__ cursor, int* __restrict__ s_src, float* __restrict__ s_ee)
{
    const int p = blockIdx.y;
    const int e = blockIdx.x * 256 + threadIdx.x;
    if (e >= EE) return;
    const int s = src[p * EE + e];
    const int d = dst[p * EE + e];
    const float4 a = ((const float4*)el)[p * NN + s];
    const float4 b = ((const float4*)er)[p * NN + d];
    float4 o;
    {
        float t0 = a.x + b.x, t1 = a.y + b.y, t2 = a.z + b.z, t3 = a.w + b.w;
        t0 = t0 > 0.f ? t0 : 0.2f * t0;
        t1 = t1 > 0.f ? t1 : 0.2f * t1;
        t2 = t2 > 0.f ? t2 : 0.2f * t2;
        t3 = t3 > 0.f ? t3 : 0.2f * t3;
        o = make_float4(expf(t0), expf(t1), expf(t2), expf(t3));
    }
    const int slot = atomicAdd(&cursor[p * NN + d], 1);
    s_src[p * EE + slot] = s;
    ((float4*)s_ee)[p * EE + slot] = o;
}

// ---------------- aggregation: one wave per dst node, no atomics ---------
// z_out = elu( (sum_e ee*feat[src]) / (sum_e ee) ); feat is bf16
__global__ __launch_bounds__(256) void k_agg(
    const int* __restrict__ row_start, const int* __restrict__ s_src,
    const float* __restrict__ s_ee, const unsigned short* __restrict__ featb,
    float* __restrict__ z)
{
    const int p = blockIdx.y;
    const int w = threadIdx.x >> 6;
    const int lane = threadIdx.x & 63;
    const int n = blockIdx.x * 4 + w;
    if (n >= NN) return;
    const int st = row_start[p * (NN + 1) + n];
    const int en = row_start[p * (NN + 1) + n + 1];

    const int h = lane >> 4;   // head of cols 2*lane, 2*lane+1
    const int* ss = s_src + (size_t)p * EE;
    const float4* ee4 = (const float4*)s_ee + (size_t)p * EE;
    const unsigned short* fbase = featb + (size_t)p * NN * 128;

    float acc0 = 0.f, acc1 = 0.f, za = 0.f;
    for (int i = st; i < en; ++i) {
        const int sn = ss[i];
        const float4 e4 = ee4[i];
        const float ea = (h < 2) ? (h == 0 ? e4.x : e4.y) : (h == 2 ? e4.z : e4.w);
        const unsigned int u = ((const unsigned int*)(fbase + (size_t)sn * 128))[lane];
        const float f0 = __uint_as_float(u << 16);
        const float f1 = __uint_as_float(u & 0xFFFF0000u);
        acc0 += ea * f0;
        acc1 += ea * f1;
        za += ea;
    }
    float v0 = 0.f, v1 = 0.f;
    if (en > st) { const float iz = 1.f / za; v0 = acc0 * iz; v1 = acc1 * iz; }
    v0 = v0 > 0.f ? v0 : (expf(v0) - 1.f);
    v1 = v1 > 0.f ? v1 : (expf(v1) - 1.f);
    const size_t o = (size_t)(p * NN + n) * 128;
    ((float2*)(z + o))[lane] = make_float2(v0, v1);
}

// ---------------- K5: semantic scores (z already elu'd) ----------------
__global__ __launch_bounds__(256) void k_sem_score(
    const float* __restrict__ z, const float* __restrict__ w1,
    const float* __restrict__ b1, const float* __restrict__ w2,
    float* __restrict__ wsem)
{
    __shared__ float sZ[64 * 128];
    __shared__ float sPart[8];
    const int tid = threadIdx.x;
    const int p  = blockIdx.y;
    const int n0 = blockIdx.x * 64;

    float4* sZ4 = (float4*)sZ;
    for (int i = tid; i < 2048; i += 256) {
        const int row = i >> 5, c4 = i & 31;
        float4 v = make_float4(0.f, 0.f, 0.f, 0.f);
        if (n0 + row < NN)
            v = ((const float4*)(z + (size_t)(p * NN + n0 + row) * 128))[c4];
        sZ4[i] = v;
    }
    __syncthreads();

    const int tc = tid & 31;
    const int tr = tid >> 5;
    const float4* w14 = (const float4*)w1;

    float4 acc[8];
    #pragma unroll
    for (int r = 0; r < 8; ++r) acc[r] = make_float4(0.f, 0.f, 0.f, 0.f);

    for (int kq = 0; kq < 32; ++kq) {
        const float4 wv0 = w14[(4 * kq + 0) * 32 + tc];
        const float4 wv1 = w14[(4 * kq + 1) * 32 + tc];
        const float4 wv2 = w14[(4 * kq + 2) * 32 + tc];
        const float4 wv3 = w14[(4 * kq + 3) * 32 + tc];
        #pragma unroll
        for (int r = 0; r < 8; ++r) {
            const float4 zv = sZ4[(tr * 8 + r) * 32 + kq];
            fma4(acc[r], zv.x, wv0);
            fma4(acc[r], zv.y, wv1);
            fma4(acc[r], zv.z, wv2);
            fma4(acc[r], zv.w, wv3);
        }
    }

    const float4 bb = ((const float4*)b1)[tc];
    const float4 ww = ((const float4*)w2)[tc];

    float local = 0.f;
    for (int r = 0; r < 8; ++r) {
        float pr = tanhf(acc[r].x + bb.x) * ww.x
                 + tanhf(acc[r].y + bb.y) * ww.y
                 + tanhf(acc[r].z + bb.z) * ww.z
                 + tanhf(acc[r].w + bb.w) * ww.w;
        pr += __shfl_xor(pr, 1);
        pr += __shfl_xor(pr, 2);
        pr += __shfl_xor(pr, 4);
        pr += __shfl_xor(pr, 8);
        pr += __shfl_xor(pr, 16);
        if (tc == 0 && (n0 + tr * 8 + r) < NN) local += pr;
    }
    if (tc == 0) sPart[tr] = local;
    __syncthreads();
    if (tid == 0) {
        float t = 0.f;
        for (int i = 0; i < 8; ++i) t += sPart[i];
        atomicAdd(&wsem[p], t);
    }
}

// ---------------- K6: bsem = softmax(wsem / N) ----------------
__global__ void k_bsem(const float* __restrict__ wsem, float* __restrict__ bsem)
{
    if (threadIdx.x == 0 && blockIdx.x == 0) {
        float w[PP];
        for (int p = 0; p < PP; ++p) w[p] = wsem[p] / (float)NN;
        float m = fmaxf(w[0], fmaxf(w[1], w[2]));
        float s = 0.f;
        for (int p = 0; p < PP; ++p) { w[p] = expf(w[p] - m); s += w[p]; }
        for (int p = 0; p < PP; ++p) bsem[p] = w[p] / s;
    }
}

// ---------------- K7: out = sum_p bsem[p] * z_p (z already elu'd) --------
__global__ __launch_bounds__(256) void k_final(
    const float* __restrict__ z, const float* __restrict__ bsem,
    float* __restrict__ out)
{
    const int i = blockIdx.x * 256 + threadIdx.x;
    if (i >= NN * 128) return;
    const float b0 = bsem[0], b1 = bsem[1], b2 = bsem[2];
    const float v0 = z[i];
    const float v1 = z[(size_t)NN * 128 + i];
    const float v2 = z[(size_t)2 * NN * 128 + i];
    out[i] = b0 * v0 + b1 * v1 + b2 * v2;
}

extern "C" void kernel_launch(void* const* d_in, const int* in_sizes, int n_in,
                              void* d_out, int out_size, void* d_ws, size_t ws_size,
                              hipStream_t stream) {
    const float* h      = (const float*)d_in[0];
    const float* c      = (const float*)d_in[1];
    const float* fa_w1  = (const float*)d_in[2];
    const float* fa_b1  = (const float*)d_in[3];
    const float* fa_w2  = (const float*)d_in[4];
    const float* gat_W  = (const float*)d_in[5];
    const float* attn_l = (const float*)d_in[6];
    const float* attn_r = (const float*)d_in[7];
    const float* sa_w1  = (const float*)d_in[8];
    const float* sa_b1  = (const float*)d_in[9];
    const float* sa_w2  = (const float*)d_in[10];
    const int*   src    = (const int*)d_in[11];
    const int*   dst    = (const int*)d_in[12];
    float* out = (float*)d_out;

    float* ws = (float*)d_ws;
    float* x     = ws;                       // 6,400,000 f
    // x region is dead after k_gat_gemm; reuse for sorted edge arrays
    int*   s_src = (int*)ws;                 // 1,200,000 i (aliases x)
    float* s_ee  = ws + 1200000;             // 4,800,000 f (aliases x)
    float* w_fa  = ws + 6400000;             // 1,000,000 f
    unsigned short* featb = (unsigned short*)(ws + 7400000); // 19,200,000 bf16 = 9.6M f
    float* el    = ws + 17000000;            //    600,000 f
    float* er    = el + 600000;              //    600,000 f
    float* z     = er + 600000;              // 19,200,000 f
    int*   row_start = (int*)(z + 19200000); // 150,003 i
    int*   cursor    = row_start + 150003;   // 150,000 i
    int*   psum      = cursor + 150000;      // 588 i
    int*   deg       = psum + 588;           // 150,000 i
    float* wsem      = (float*)(deg + 150000); // 4 f
    float* bsem      = wsem + 4;             // 4 f

    hipMemsetAsync(deg, 0, (size_t)(150000 + 4) * sizeof(float), stream);

    k_fa_w<<<(NN * 5 + 255) / 256, 256, 0, stream>>>(c, fa_w1, fa_b1, fa_w2, w_fa);
    k_fa_emb<<<(NN + 3) / 4, 256, 0, stream>>>(h, c, w_fa, x);
    k_gat_gemm<<<dim3((NN + 63) / 64, PP), 256, 0, stream>>>(x, gat_W, attn_l, attn_r, featb, el, er);
    k_hist<<<dim3((EE + 255) / 256, PP), 256, 0, stream>>>(dst, deg);
    k_partial<<<dim3(NBLK, PP), 256, 0, stream>>>(deg, psum);
    k_scanpsum<<<PP, 64, 0, stream>>>(psum);
    k_scanfinal<<<dim3(NBLK, PP), 256, 0, stream>>>(deg, psum, row_start, cursor);
    k_scatter<<<dim3((EE + 255) / 256, PP), 256, 0, stream>>>(src, dst, el, er, cursor, s_src, s_ee);
    k_agg<<<dim3((NN + 3) / 4, PP), 256, 0, stream>>>(row_start, s_src, s_ee, featb, z);
    k_sem_score<<<dim3((NN + 63) / 64, PP), 256, 0, stream>>>(z, sa_w1, sa_b1, sa_w2, wsem);
    k_bsem<<<1, 64, 0, stream>>>(wsem, bsem);
    k_final<<<(NN * 128 + 255) / 256, 256, 0, stream>>>(z, bsem, out);
}

// Round 6
// 824.703 us; speedup vs baseline: 1.1068x; 1.1068x over previous
//
#include <hip/hip_runtime.h>
#include <hip/hip_bf16.h>

#define NN 50000
#define EE 400000
#define PP 3
#define NBLK 196   // ceil(NN/256)
// H=4, D=32, IN=128, HD=128

__device__ __forceinline__ float eluf(float v) {
    return v > 0.f ? v : (expf(v) - 1.f);
}

__device__ __forceinline__ void fma4(float4& a, float s, const float4& w) {
    a.x += s * w.x; a.y += s * w.y; a.z += s * w.z; a.w += s * w.w;
}

__device__ __forceinline__ unsigned short f2bf(float f) {
    unsigned int u = __float_as_uint(f);
    u = (u + 0x7FFFu + ((u >> 16) & 1u)) >> 16;
    return (unsigned short)u;
}
__device__ __forceinline__ float bf_lo(unsigned int u) { return __uint_as_float(u << 16); }
__device__ __forceinline__ float bf_hi(unsigned int u) { return __uint_as_float(u & 0xFFFF0000u); }

// ---------------- K1a: w[n,r] = tanh(C[n,r,:]@W1 + b1)@w2 ----------------
__global__ __launch_bounds__(256) void k_fa_w(
    const float* __restrict__ c, const float* __restrict__ w1,
    const float* __restrict__ b1, const float* __restrict__ w2,
    float* __restrict__ wout)
{
    __shared__ float sW1[42 * 16];
    const int tid = threadIdx.x;
    for (int i = tid; i < 672; i += 256) sW1[i] = w1[i];
    __syncthreads();

    const int t = blockIdx.x * 256 + tid;
    if (t >= NN * 5) return;
    const int n = t / 5;
    const int q = t - 5 * n;

    const float2* base = (const float2*)(c + (size_t)n * 840 + q * 168);
    const float4* sW4 = (const float4*)sW1;

    float4 acc[4][4];
    #pragma unroll
    for (int r = 0; r < 4; ++r)
        #pragma unroll
        for (int jq = 0; jq < 4; ++jq) acc[r][jq] = make_float4(0.f, 0.f, 0.f, 0.f);

    #pragma unroll 3
    for (int i2 = 0; i2 < 21; ++i2) {
        const float4 wa0 = sW4[(2 * i2) * 4 + 0];
        const float4 wa1 = sW4[(2 * i2) * 4 + 1];
        const float4 wa2 = sW4[(2 * i2) * 4 + 2];
        const float4 wa3 = sW4[(2 * i2) * 4 + 3];
        const float4 wb0 = sW4[(2 * i2 + 1) * 4 + 0];
        const float4 wb1 = sW4[(2 * i2 + 1) * 4 + 1];
        const float4 wb2 = sW4[(2 * i2 + 1) * 4 + 2];
        const float4 wb3 = sW4[(2 * i2 + 1) * 4 + 3];
        #pragma unroll
        for (int r = 0; r < 4; ++r) {
            const float2 v = base[r * 21 + i2];
            fma4(acc[r][0], v.x, wa0); fma4(acc[r][1], v.x, wa1);
            fma4(acc[r][2], v.x, wa2); fma4(acc[r][3], v.x, wa3);
            fma4(acc[r][0], v.y, wb0); fma4(acc[r][1], v.y, wb1);
            fma4(acc[r][2], v.y, wb2); fma4(acc[r][3], v.y, wb3);
        }
    }

    float4 bb[4], ww[4];
    #pragma unroll
    for (int jq = 0; jq < 4; ++jq) {
        bb[jq] = ((const float4*)b1)[jq];
        ww[jq] = ((const float4*)w2)[jq];
    }
    float* wo = wout + (size_t)n * 20 + q * 4;
    #pragma unroll
    for (int r = 0; r < 4; ++r) {
        float s = 0.f;
        #pragma unroll
        for (int jq = 0; jq < 4; ++jq) {
            s += tanhf(acc[r][jq].x + bb[jq].x) * ww[jq].x;
            s += tanhf(acc[r][jq].y + bb[jq].y) * ww[jq].y;
            s += tanhf(acc[r][jq].z + bb[jq].z) * ww[jq].z;
            s += tanhf(acc[r][jq].w + bb[jq].w) * ww[jq].w;
        }
        wo[r] = s;
    }
}

// ---------------- K1b: softmax(w) weighted sum + concat h -> x ----------
__global__ __launch_bounds__(256) void k_fa_emb(
    const float* __restrict__ h, const float* __restrict__ c,
    const float* __restrict__ w, float* __restrict__ x)
{
    const int wid = threadIdx.x >> 6, lane = threadIdx.x & 63;
    const int n = blockIdx.x * 4 + wid;
    if (n >= NN) return;

    const float* wn = w + (size_t)n * 20;
    float wv[20];
    #pragma unroll
    for (int r = 0; r < 20; ++r) wv[r] = wn[r];
    float m = wv[0];
    #pragma unroll
    for (int r = 1; r < 20; ++r) m = fmaxf(m, wv[r]);
    float s = 0.f;
    #pragma unroll
    for (int r = 0; r < 20; ++r) { wv[r] = expf(wv[r] - m); s += wv[r]; }
    const float inv = 1.f / s;

    if (lane < 42) {
        const float* cn = c + (size_t)n * 840;
        float acc = 0.f;
        #pragma unroll
        for (int r = 0; r < 20; ++r) acc += wv[r] * cn[r * 42 + lane];
        x[(size_t)n * 128 + 86 + lane] = acc * inv;
    }
    x[(size_t)n * 128 + lane] = h[(size_t)n * 86 + lane];
    if (lane < 22)
        x[(size_t)n * 128 + 64 + lane] = h[(size_t)n * 86 + 64 + lane];
}

// ---------------- K2: feat(bf16) = x @ W_p, plus el/er epilogue ----------
__global__ __launch_bounds__(256) void k_gat_gemm(
    const float* __restrict__ x, const float* __restrict__ W,
    const float* __restrict__ attn_l, const float* __restrict__ attn_r,
    unsigned short* __restrict__ featb, float* __restrict__ el, float* __restrict__ er)
{
    __shared__ float sX[64 * 128];
    const int tid = threadIdx.x;
    const int p  = blockIdx.y;
    const int n0 = blockIdx.x * 64;

    float4* sX4 = (float4*)sX;
    for (int i = tid; i < 2048; i += 256) {
        const int row = i >> 5, c4 = i & 31;
        float4 v = make_float4(0.f, 0.f, 0.f, 0.f);
        if (n0 + row < NN) v = ((const float4*)(x + (size_t)(n0 + row) * 128))[c4];
        sX4[i] = v;
    }
    __syncthreads();

    const int tc = tid & 31;   // 4-col group
    const int tr = tid >> 5;   // 8-row group
    const float4* Wp4 = (const float4*)(W + (size_t)p * 128 * 128);

    float4 acc[8];
    #pragma unroll
    for (int r = 0; r < 8; ++r) acc[r] = make_float4(0.f, 0.f, 0.f, 0.f);

    for (int kq = 0; kq < 32; ++kq) {
        const float4 wv0 = Wp4[(4 * kq + 0) * 32 + tc];
        const float4 wv1 = Wp4[(4 * kq + 1) * 32 + tc];
        const float4 wv2 = Wp4[(4 * kq + 2) * 32 + tc];
        const float4 wv3 = Wp4[(4 * kq + 3) * 32 + tc];
        #pragma unroll
        for (int r = 0; r < 8; ++r) {
            const float4 xv = sX4[(tr * 8 + r) * 32 + kq];
            fma4(acc[r], xv.x, wv0);
            fma4(acc[r], xv.y, wv1);
            fma4(acc[r], xv.z, wv2);
            fma4(acc[r], xv.w, wv3);
        }
    }

    float4 al, ar;
    {
        al = ((const float4*)(attn_l + p * 128))[tc];
        ar = ((const float4*)(attn_r + p * 128))[tc];
    }
    const int hh = tc >> 3;
    for (int r = 0; r < 8; ++r) {
        const int n = n0 + tr * 8 + r;
        const bool ok = n < NN;
        if (ok) {
            ushort4 sv;
            sv.x = f2bf(acc[r].x); sv.y = f2bf(acc[r].y);
            sv.z = f2bf(acc[r].z); sv.w = f2bf(acc[r].w);
            ((ushort4*)(featb + (size_t)(p * NN + n) * 128))[tc] = sv;
        }
        float pl = acc[r].x*al.x + acc[r].y*al.y + acc[r].z*al.z + acc[r].w*al.w;
        float pr = acc[r].x*ar.x + acc[r].y*ar.y + acc[r].z*ar.z + acc[r].w*ar.w;
        pl += __shfl_xor(pl, 1); pl += __shfl_xor(pl, 2); pl += __shfl_xor(pl, 4);
        pr += __shfl_xor(pr, 1); pr += __shfl_xor(pr, 2); pr += __shfl_xor(pr, 4);
        if (ok && (tc & 7) == 0) {
            el[(size_t)(p * NN + n) * 4 + hh] = pl;
            er[(size_t)(p * NN + n) * 4 + hh] = pr;
        }
    }
}

// ---------------- CSR build: histogram ----------------
__global__ __launch_bounds__(256) void k_hist(
    const int* __restrict__ dst, int* __restrict__ deg)
{
    const int p = blockIdx.y;
    const int e = blockIdx.x * 256 + threadIdx.x;
    if (e < EE) atomicAdd(&deg[p * NN + dst[p * EE + e]], 1);
}

// ---------------- CSR build: per-block partial sums ----------------
__global__ __launch_bounds__(256) void k_partial(
    const int* __restrict__ deg, int* __restrict__ psum)
{
    __shared__ int s[256];
    const int p = blockIdx.y;
    const int i = blockIdx.x * 256 + threadIdx.x;
    s[threadIdx.x] = (i < NN) ? deg[p * NN + i] : 0;
    __syncthreads();
    for (int off = 128; off > 0; off >>= 1) {
        if (threadIdx.x < off) s[threadIdx.x] += s[threadIdx.x + off];
        __syncthreads();
    }
    if (threadIdx.x == 0) psum[p * NBLK + blockIdx.x] = s[0];
}

// ---------------- CSR build: scan block partials (tiny) ----------------
__global__ void k_scanpsum(int* __restrict__ psum)
{
    const int p = blockIdx.x;
    if (threadIdx.x == 0) {
        int run = 0;
        for (int i = 0; i < NBLK; ++i) {
            int t = psum[p * NBLK + i];
            psum[p * NBLK + i] = run;
            run += t;
        }
    }
}

// ---------------- CSR build: final exclusive scan -> row_start, cursor ----
__global__ __launch_bounds__(256) void k_scanfinal(
    const int* __restrict__ deg, const int* __restrict__ psum,
    int* __restrict__ row_start, int* __restrict__ cursor)
{
    __shared__ int s[256];
    const int p = blockIdx.y, t = threadIdx.x;
    const int i = blockIdx.x * 256 + t;
    const int v = (i < NN) ? deg[p * NN + i] : 0;
    s[t] = v;
    __syncthreads();
    for (int off = 1; off < 256; off <<= 1) {
        int xv = 0;
        if (t >= off) xv = s[t - off];
        __syncthreads();
        s[t] += xv;
        __syncthreads();
    }
    const int excl = s[t] - v + psum[p * NBLK + blockIdx.x];
    if (i < NN) {
        row_start[p * (NN + 1) + i] = excl;
        cursor[p * NN + i] = excl;
        if (i == NN - 1) row_start[p * (NN + 1) + NN] = excl + v;
    }
}

// ---------------- scatter: sorted src + per-edge exp(leaky(el+er)) -------
__global__ __launch_bounds__(256) void k_scatter(
    const int* __restrict__ src, const int* __restrict__ dst,
    const float* __restrict__ el, const float* __restrict__ er,
    int* __restrict__ cursor, int* __restrict__ s_src, float* __restrict__ s_ee)
{
    const int p = blockIdx.y;
    const int e = blockIdx.x * 256 + threadIdx.x;
    if (e >= EE) return;
    const int s = src[p * EE + e];
    const int d = dst[p * EE + e];
    const float4 a = ((const float4*)el)[p * NN + s];
    const float4 b = ((const float4*)er)[p * NN + d];
    float4 o;
    {
        float t0 = a.x + b.x, t1 = a.y + b.y, t2 = a.z + b.z, t3 = a.w + b.w;
        t0 = t0 > 0.f ? t0 : 0.2f * t0;
        t1 = t1 > 0.f ? t1 : 0.2f * t1;
        t2 = t2 > 0.f ? t2 : 0.2f * t2;
        t3 = t3 > 0.f ? t3 : 0.2f * t3;
        o = make_float4(expf(t0), expf(t1), expf(t2), expf(t3));
    }
    const int slot = atomicAdd(&cursor[p * NN + d], 1);
    s_src[p * EE + slot] = s;
    ((float4*)s_ee)[p * EE + slot] = o;
}

// ---------------- aggregation: one wave per dst node, 4x unrolled --------
// z_out(bf16) = elu( (sum_e ee*feat[src]) / (sum_e ee) )
__global__ __launch_bounds__(256) void k_agg(
    const int* __restrict__ row_start, const int* __restrict__ s_src,
    const float* __restrict__ s_ee, const unsigned short* __restrict__ featb,
    unsigned int* __restrict__ zb)
{
    const int p = blockIdx.y;
    const int w = threadIdx.x >> 6;
    const int lane = threadIdx.x & 63;
    const int n = blockIdx.x * 4 + w;
    if (n >= NN) return;
    const int st = row_start[p * (NN + 1) + n];
    const int en = row_start[p * (NN + 1) + n + 1];

    const int h = lane >> 4;   // head of cols 2*lane, 2*lane+1
    const int* ss = s_src + (size_t)p * EE;
    const float4* ee4 = (const float4*)s_ee + (size_t)p * EE;
    const unsigned short* fbase = featb + (size_t)p * NN * 128;

    float acc0 = 0.f, acc1 = 0.f, za = 0.f;
    int i = st;
    for (; i + 4 <= en; i += 4) {
        const int sn0 = ss[i], sn1 = ss[i + 1], sn2 = ss[i + 2], sn3 = ss[i + 3];
        const float4 q0 = ee4[i], q1 = ee4[i + 1], q2 = ee4[i + 2], q3 = ee4[i + 3];
        const unsigned int u0 = ((const unsigned int*)(fbase + (size_t)sn0 * 128))[lane];
        const unsigned int u1 = ((const unsigned int*)(fbase + (size_t)sn1 * 128))[lane];
        const unsigned int u2 = ((const unsigned int*)(fbase + (size_t)sn2 * 128))[lane];
        const unsigned int u3 = ((const unsigned int*)(fbase + (size_t)sn3 * 128))[lane];
        const float e0 = (h < 2) ? (h == 0 ? q0.x : q0.y) : (h == 2 ? q0.z : q0.w);
        const float e1 = (h < 2) ? (h == 0 ? q1.x : q1.y) : (h == 2 ? q1.z : q1.w);
        const float e2 = (h < 2) ? (h == 0 ? q2.x : q2.y) : (h == 2 ? q2.z : q2.w);
        const float e3 = (h < 2) ? (h == 0 ? q3.x : q3.y) : (h == 2 ? q3.z : q3.w);
        acc0 += e0 * bf_lo(u0) + e1 * bf_lo(u1) + e2 * bf_lo(u2) + e3 * bf_lo(u3);
        acc1 += e0 * bf_hi(u0) + e1 * bf_hi(u1) + e2 * bf_hi(u2) + e3 * bf_hi(u3);
        za += (e0 + e1) + (e2 + e3);
    }
    for (; i < en; ++i) {
        const int sn = ss[i];
        const float4 q = ee4[i];
        const unsigned int u = ((const unsigned int*)(fbase + (size_t)sn * 128))[lane];
        const float e = (h < 2) ? (h == 0 ? q.x : q.y) : (h == 2 ? q.z : q.w);
        acc0 += e * bf_lo(u);
        acc1 += e * bf_hi(u);
        za += e;
    }
    float v0 = 0.f, v1 = 0.f;
    if (en > st) { const float iz = 1.f / za; v0 = acc0 * iz; v1 = acc1 * iz; }
    v0 = v0 > 0.f ? v0 : (expf(v0) - 1.f);
    v1 = v1 > 0.f ? v1 : (expf(v1) - 1.f);
    zb[(size_t)(p * NN + n) * 64 + lane] =
        (unsigned int)f2bf(v0) | ((unsigned int)f2bf(v1) << 16);
}

// ---------------- K5: semantic scores (z bf16, already elu'd) ------------
__global__ __launch_bounds__(256) void k_sem_score(
    const unsigned int* __restrict__ zb, const float* __restrict__ w1,
    const float* __restrict__ b1, const float* __restrict__ w2,
    float* __restrict__ wsem)
{
    __shared__ float sZ[64 * 128];
    __shared__ float sPart[8];
    const int tid = threadIdx.x;
    const int p  = blockIdx.y;
    const int n0 = blockIdx.x * 64;

    float4* sZ4 = (float4*)sZ;
    for (int i = tid; i < 2048; i += 256) {
        const int row = i >> 5, c4 = i & 31;
        float4 v = make_float4(0.f, 0.f, 0.f, 0.f);
        if (n0 + row < NN) {
            const uint2 u = ((const uint2*)(zb + (size_t)(p * NN + n0 + row) * 64))[c4];
            v.x = bf_lo(u.x); v.y = bf_hi(u.x); v.z = bf_lo(u.y); v.w = bf_hi(u.y);
        }
        sZ4[i] = v;
    }
    __syncthreads();

    const int tc = tid & 31;
    const int tr = tid >> 5;
    const float4* w14 = (const float4*)w1;

    float4 acc[8];
    #pragma unroll
    for (int r = 0; r < 8; ++r) acc[r] = make_float4(0.f, 0.f, 0.f, 0.f);

    for (int kq = 0; kq < 32; ++kq) {
        const float4 wv0 = w14[(4 * kq + 0) * 32 + tc];
        const float4 wv1 = w14[(4 * kq + 1) * 32 + tc];
        const float4 wv2 = w14[(4 * kq + 2) * 32 + tc];
        const float4 wv3 = w14[(4 * kq + 3) * 32 + tc];
        #pragma unroll
        for (int r = 0; r < 8; ++r) {
            const float4 zv = sZ4[(tr * 8 + r) * 32 + kq];
            fma4(acc[r], zv.x, wv0);
            fma4(acc[r], zv.y, wv1);
            fma4(acc[r], zv.z, wv2);
            fma4(acc[r], zv.w, wv3);
        }
    }

    const float4 bb = ((const float4*)b1)[tc];
    const float4 ww = ((const float4*)w2)[tc];

    float local = 0.f;
    for (int r = 0; r < 8; ++r) {
        float pr = tanhf(acc[r].x + bb.x) * ww.x
                 + tanhf(acc[r].y + bb.y) * ww.y
                 + tanhf(acc[r].z + bb.z) * ww.z
                 + tanhf(acc[r].w + bb.w) * ww.w;
        pr += __shfl_xor(pr, 1);
        pr += __shfl_xor(pr, 2);
        pr += __shfl_xor(pr, 4);
        pr += __shfl_xor(pr, 8);
        pr += __shfl_xor(pr, 16);
        if (tc == 0 && (n0 + tr * 8 + r) < NN) local += pr;
    }
    if (tc == 0) sPart[tr] = local;
    __syncthreads();
    if (tid == 0) {
        float t = 0.f;
        for (int i = 0; i < 8; ++i) t += sPart[i];
        atomicAdd(&wsem[p], t);
    }
}

// ---------------- K6: bsem = softmax(wsem / N) ----------------
__global__ void k_bsem(const float* __restrict__ wsem, float* __restrict__ bsem)
{
    if (threadIdx.x == 0 && blockIdx.x == 0) {
        float w[PP];
        for (int p = 0; p < PP; ++p) w[p] = wsem[p] / (float)NN;
        float m = fmaxf(w[0], fmaxf(w[1], w[2]));
        float s = 0.f;
        for (int p = 0; p < PP; ++p) { w[p] = expf(w[p] - m); s += w[p]; }
        for (int p = 0; p < PP; ++p) bsem[p] = w[p] / s;
    }
}

// ---------------- K7: out = sum_p bsem[p] * z_p (z bf16, elu'd) ----------
__global__ __launch_bounds__(256) void k_final(
    const unsigned int* __restrict__ zb, const float* __restrict__ bsem,
    float* __restrict__ out)
{
    const int i = blockIdx.x * 256 + threadIdx.x;
    if (i >= NN * 64) return;
    const float b0 = bsem[0], b1 = bsem[1], b2 = bsem[2];
    const unsigned int u0 = zb[i];
    const unsigned int u1 = zb[(size_t)NN * 64 + i];
    const unsigned int u2 = zb[(size_t)2 * NN * 64 + i];
    float2 o;
    o.x = b0 * bf_lo(u0) + b1 * bf_lo(u1) + b2 * bf_lo(u2);
    o.y = b0 * bf_hi(u0) + b1 * bf_hi(u1) + b2 * bf_hi(u2);
    ((float2*)out)[i] = o;
}

extern "C" void kernel_launch(void* const* d_in, const int* in_sizes, int n_in,
                              void* d_out, int out_size, void* d_ws, size_t ws_size,
                              hipStream_t stream) {
    const float* h      = (const float*)d_in[0];
    const float* c      = (const float*)d_in[1];
    const float* fa_w1  = (const float*)d_in[2];
    const float* fa_b1  = (const float*)d_in[3];
    const float* fa_w2  = (const float*)d_in[4];
    const float* gat_W  = (const float*)d_in[5];
    const float* attn_l = (const float*)d_in[6];
    const float* attn_r = (const float*)d_in[7];
    const float* sa_w1  = (const float*)d_in[8];
    const float* sa_b1  = (const float*)d_in[9];
    const float* sa_w2  = (const float*)d_in[10];
    const int*   src    = (const int*)d_in[11];
    const int*   dst    = (const int*)d_in[12];
    float* out = (float*)d_out;

    float* ws = (float*)d_ws;
    float* x     = ws;                       // 6,400,000 f
    // x region is dead after k_gat_gemm; reuse for sorted edge arrays
    int*   s_src = (int*)ws;                 // 1,200,000 i (aliases x)
    float* s_ee  = ws + 1200000;             // 4,800,000 f (aliases x)
    float* w_fa  = ws + 6400000;             // 1,000,000 f
    unsigned short* featb = (unsigned short*)(ws + 7400000); // 19.2M bf16 = 9.6M f
    float* el    = ws + 17000000;            //    600,000 f
    float* er    = el + 600000;              //    600,000 f
    unsigned int* zb = (unsigned int*)(er + 600000); // 9,600,000 u32 (bf16 pairs)
    int*   row_start = (int*)(ws + 27800000); // 150,003 i
    int*   cursor    = row_start + 150003;   // 150,000 i
    int*   psum      = cursor + 150000;      // 588 i
    int*   deg       = psum + 588;           // 150,000 i
    float* wsem      = (float*)(deg + 150000); // 4 f
    float* bsem      = wsem + 4;             // 4 f

    hipMemsetAsync(deg, 0, (size_t)(150000 + 4) * sizeof(float), stream);

    k_fa_w<<<(NN * 5 + 255) / 256, 256, 0, stream>>>(c, fa_w1, fa_b1, fa_w2, w_fa);
    k_fa_emb<<<(NN + 3) / 4, 256, 0, stream>>>(h, c, w_fa, x);
    k_gat_gemm<<<dim3((NN + 63) / 64, PP), 256, 0, stream>>>(x, gat_W, attn_l, attn_r, featb, el, er);
    k_hist<<<dim3((EE + 255) / 256, PP), 256, 0, stream>>>(dst, deg);
    k_partial<<<dim3(NBLK, PP), 256, 0, stream>>>(deg, psum);
    k_scanpsum<<<PP, 64, 0, stream>>>(psum);
    k_scanfinal<<<dim3(NBLK, PP), 256, 0, stream>>>(deg, psum, row_start, cursor);
    k_scatter<<<dim3((EE + 255) / 256, PP), 256, 0, stream>>>(src, dst, el, er, cursor, s_src, s_ee);
    k_agg<<<dim3((NN + 3) / 4, PP), 256, 0, stream>>>(row_start, s_src, s_ee, featb, zb);
    k_sem_score<<<dim3((NN + 63) / 64, PP), 256, 0, stream>>>(zb, sa_w1, sa_b1, sa_w2, wsem);
    k_bsem<<<1, 64, 0, stream>>>(wsem, bsem);
    k_final<<<(NN * 64 + 255) / 256, 256, 0, stream>>>(zb, bsem, out);
}

// Round 7
// 716.511 us; speedup vs baseline: 1.2740x; 1.1510x over previous
//
#include <hip/hip_runtime.h>
#include <hip/hip_bf16.h>

#define NN 50000
#define EE 400000
#define PP 3
#define NBLK 196   // ceil(NN/256)
// H=4, D=32, IN=128, HD=128

__device__ __forceinline__ float eluf(float v) {
    return v > 0.f ? v : (expf(v) - 1.f);
}

__device__ __forceinline__ void fma4(float4& a, float s, const float4& w) {
    a.x += s * w.x; a.y += s * w.y; a.z += s * w.z; a.w += s * w.w;
}

__device__ __forceinline__ unsigned short f2bf(float f) {
    unsigned int u = __float_as_uint(f);
    u = (u + 0x7FFFu + ((u >> 16) & 1u)) >> 16;
    return (unsigned short)u;
}
__device__ __forceinline__ float bf_lo(unsigned int u) { return __uint_as_float(u << 16); }
__device__ __forceinline__ float bf_hi(unsigned int u) { return __uint_as_float(u & 0xFFFF0000u); }

// ---------------- K1: fused feature attention -> x[N,128] ----------------
// one wave per node, 4 nodes/block; c staged once, coalesced, into LDS
__global__ __launch_bounds__(256) void k_fa(
    const float* __restrict__ h, const float* __restrict__ c,
    const float* __restrict__ w1, const float* __restrict__ b1,
    const float* __restrict__ w2, float* __restrict__ x)
{
    __shared__ float sC[4][840];   // 13.4 KB
    __shared__ float sW1[672];     // 2.7 KB
    __shared__ float sWr[4][20];   // row scores
    const int tid = threadIdx.x;
    const int wid = tid >> 6, lane = tid & 63;
    const int n = blockIdx.x * 4 + wid;

    for (int i = tid; i < 672; i += 256) sW1[i] = w1[i];

    if (n < NN) {
        const float4* cn4 = (const float4*)(c + (size_t)n * 840);
        float4* sC4 = (float4*)sC[wid];
        #pragma unroll
        for (int k = lane; k < 210; k += 64) sC4[k] = cn4[k];
    }
    __syncthreads();

    const int j = lane & 15, rg = lane >> 4;   // col j, row-group rg (5 rows)
    if (n < NN) {
        const float bj = b1[j], w2j = w2[j];
        float pr[5];
        #pragma unroll
        for (int rr = 0; rr < 5; ++rr) {
            const int r = rg * 5 + rr;
            float acc = bj;
            const float* row = &sC[wid][r * 42];
            #pragma unroll
            for (int i = 0; i < 42; ++i) acc += row[i] * sW1[i * 16 + j];
            pr[rr] = tanhf(acc) * w2j;
        }
        #pragma unroll
        for (int rr = 0; rr < 5; ++rr) {
            float v = pr[rr];
            v += __shfl_xor(v, 1);
            v += __shfl_xor(v, 2);
            v += __shfl_xor(v, 4);
            v += __shfl_xor(v, 8);
            pr[rr] = v;
        }
        if (j == 0) {
            #pragma unroll
            for (int rr = 0; rr < 5; ++rr) sWr[wid][rg * 5 + rr] = pr[rr];
        }
    }
    __syncthreads();

    if (n >= NN) return;
    float wv[20];
    #pragma unroll
    for (int r = 0; r < 20; ++r) wv[r] = sWr[wid][r];
    float m = wv[0];
    #pragma unroll
    for (int r = 1; r < 20; ++r) m = fmaxf(m, wv[r]);
    float s = 0.f;
    #pragma unroll
    for (int r = 0; r < 20; ++r) { wv[r] = expf(wv[r] - m); s += wv[r]; }
    const float inv = 1.f / s;

    if (lane < 42) {
        float acc = 0.f;
        #pragma unroll
        for (int r = 0; r < 20; ++r) acc += wv[r] * sC[wid][r * 42 + lane];
        x[(size_t)n * 128 + 86 + lane] = acc * inv;
    }
    x[(size_t)n * 128 + lane] = h[(size_t)n * 86 + lane];
    if (lane < 22)
        x[(size_t)n * 128 + 64 + lane] = h[(size_t)n * 86 + 64 + lane];
}

// ---------------- K2: feat(bf16) = x @ W_p, plus el/er epilogue ----------
__global__ __launch_bounds__(256) void k_gat_gemm(
    const float* __restrict__ x, const float* __restrict__ W,
    const float* __restrict__ attn_l, const float* __restrict__ attn_r,
    unsigned short* __restrict__ featb, float* __restrict__ el, float* __restrict__ er)
{
    __shared__ float sX[64 * 128];
    const int tid = threadIdx.x;
    const int p  = blockIdx.y;
    const int n0 = blockIdx.x * 64;

    float4* sX4 = (float4*)sX;
    for (int i = tid; i < 2048; i += 256) {
        const int row = i >> 5, c4 = i & 31;
        float4 v = make_float4(0.f, 0.f, 0.f, 0.f);
        if (n0 + row < NN) v = ((const float4*)(x + (size_t)(n0 + row) * 128))[c4];
        sX4[i] = v;
    }
    __syncthreads();

    const int tc = tid & 31;   // 4-col group
    const int tr = tid >> 5;   // 8-row group
    const float4* Wp4 = (const float4*)(W + (size_t)p * 128 * 128);

    float4 acc[8];
    #pragma unroll
    for (int r = 0; r < 8; ++r) acc[r] = make_float4(0.f, 0.f, 0.f, 0.f);

    for (int kq = 0; kq < 32; ++kq) {
        const float4 wv0 = Wp4[(4 * kq + 0) * 32 + tc];
        const float4 wv1 = Wp4[(4 * kq + 1) * 32 + tc];
        const float4 wv2 = Wp4[(4 * kq + 2) * 32 + tc];
        const float4 wv3 = Wp4[(4 * kq + 3) * 32 + tc];
        #pragma unroll
        for (int r = 0; r < 8; ++r) {
            const float4 xv = sX4[(tr * 8 + r) * 32 + kq];
            fma4(acc[r], xv.x, wv0);
            fma4(acc[r], xv.y, wv1);
            fma4(acc[r], xv.z, wv2);
            fma4(acc[r], xv.w, wv3);
        }
    }

    float4 al, ar;
    {
        al = ((const float4*)(attn_l + p * 128))[tc];
        ar = ((const float4*)(attn_r + p * 128))[tc];
    }
    const int hh = tc >> 3;
    for (int r = 0; r < 8; ++r) {
        const int n = n0 + tr * 8 + r;
        const bool ok = n < NN;
        if (ok) {
            ushort4 sv;
            sv.x = f2bf(acc[r].x); sv.y = f2bf(acc[r].y);
            sv.z = f2bf(acc[r].z); sv.w = f2bf(acc[r].w);
            ((ushort4*)(featb + (size_t)(p * NN + n) * 128))[tc] = sv;
        }
        float pl = acc[r].x*al.x + acc[r].y*al.y + acc[r].z*al.z + acc[r].w*al.w;
        float pr = acc[r].x*ar.x + acc[r].y*ar.y + acc[r].z*ar.z + acc[r].w*ar.w;
        pl += __shfl_xor(pl, 1); pl += __shfl_xor(pl, 2); pl += __shfl_xor(pl, 4);
        pr += __shfl_xor(pr, 1); pr += __shfl_xor(pr, 2); pr += __shfl_xor(pr, 4);
        if (ok && (tc & 7) == 0) {
            el[(size_t)(p * NN + n) * 4 + hh] = pl;
            er[(size_t)(p * NN + n) * 4 + hh] = pr;
        }
    }
}

// ---------------- CSR build: histogram ----------------
__global__ __launch_bounds__(256) void k_hist(
    const int* __restrict__ dst, int* __restrict__ deg)
{
    const int p = blockIdx.y;
    const int e = blockIdx.x * 256 + threadIdx.x;
    if (e < EE) atomicAdd(&deg[p * NN + dst[p * EE + e]], 1);
}

// ---------------- CSR build: per-block partial sums ----------------
__global__ __launch_bounds__(256) void k_partial(
    const int* __restrict__ deg, int* __restrict__ psum)
{
    __shared__ int s[256];
    const int p = blockIdx.y;
    const int i = blockIdx.x * 256 + threadIdx.x;
    s[threadIdx.x] = (i < NN) ? deg[p * NN + i] : 0;
    __syncthreads();
    for (int off = 128; off > 0; off >>= 1) {
        if (threadIdx.x < off) s[threadIdx.x] += s[threadIdx.x + off];
        __syncthreads();
    }
    if (threadIdx.x == 0) psum[p * NBLK + blockIdx.x] = s[0];
}

// ---------------- CSR build: scan block partials (tiny) ----------------
__global__ void k_scanpsum(int* __restrict__ psum)
{
    const int p = blockIdx.x;
    if (threadIdx.x == 0) {
        int run = 0;
        for (int i = 0; i < NBLK; ++i) {
            int t = psum[p * NBLK + i];
            psum[p * NBLK + i] = run;
            run += t;
        }
    }
}

// ---------------- CSR build: final exclusive scan -> row_start, cursor ----
__global__ __launch_bounds__(256) void k_scanfinal(
    const int* __restrict__ deg, const int* __restrict__ psum,
    int* __restrict__ row_start, int* __restrict__ cursor)
{
    __shared__ int s[256];
    const int p = blockIdx.y, t = threadIdx.x;
    const int i = blockIdx.x * 256 + t;
    const int v = (i < NN) ? deg[p * NN + i] : 0;
    s[t] = v;
    __syncthreads();
    for (int off = 1; off < 256; off <<= 1) {
        int xv = 0;
        if (t >= off) xv = s[t - off];
        __syncthreads();
        s[t] += xv;
        __syncthreads();
    }
    const int excl = s[t] - v + psum[p * NBLK + blockIdx.x];
    if (i < NN) {
        row_start[p * (NN + 1) + i] = excl;
        cursor[p * NN + i] = excl;
        if (i == NN - 1) row_start[p * (NN + 1) + NN] = excl + v;
    }
}

// ---------------- scatter: sorted src + per-edge exp(leaky(el+er)) -------
__global__ __launch_bounds__(256) void k_scatter(
    const int* __restrict__ src, const int* __restrict__ dst,
    const float* __restrict__ el, const float* __restrict__ er,
    int* __restrict__ cursor, int* __restrict__ s_src, float* __restrict__ s_ee)
{
    const int p = blockIdx.y;
    const int e = blockIdx.x * 256 + threadIdx.x;
    if (e >= EE) return;
    const int s = src[p * EE + e];
    const int d = dst[p * EE + e];
    const float4 a = ((const float4*)el)[p * NN + s];
    const float4 b = ((const float4*)er)[p * NN + d];
    float4 o;
    {
        float t0 = a.x + b.x, t1 = a.y + b.y, t2 = a.z + b.z, t3 = a.w + b.w;
        t0 = t0 > 0.f ? t0 : 0.2f * t0;
        t1 = t1 > 0.f ? t1 : 0.2f * t1;
        t2 = t2 > 0.f ? t2 : 0.2f * t2;
        t3 = t3 > 0.f ? t3 : 0.2f * t3;
        o = make_float4(expf(t0), expf(t1), expf(t2), expf(t3));
    }
    const int slot = atomicAdd(&cursor[p * NN + d], 1);
    s_src[p * EE + slot] = s;
    ((float4*)s_ee)[p * EE + slot] = o;
}

// ---------------- aggregation: one wave per dst node, 4x unrolled --------
// z_out(bf16) = elu( (sum_e ee*feat[src]) / (sum_e ee) )
__global__ __launch_bounds__(256) void k_agg(
    const int* __restrict__ row_start, const int* __restrict__ s_src,
    const float* __restrict__ s_ee, const unsigned short* __restrict__ featb,
    unsigned int* __restrict__ zb)
{
    const int p = blockIdx.y;
    const int w = threadIdx.x >> 6;
    const int lane = threadIdx.x & 63;
    const int n = blockIdx.x * 4 + w;
    if (n >= NN) return;
    const int st = row_start[p * (NN + 1) + n];
    const int en = row_start[p * (NN + 1) + n + 1];

    const int h = lane >> 4;   // head of cols 2*lane, 2*lane+1
    const int* ss = s_src + (size_t)p * EE;
    const float4* ee4 = (const float4*)s_ee + (size_t)p * EE;
    const unsigned short* fbase = featb + (size_t)p * NN * 128;

    float acc0 = 0.f, acc1 = 0.f, za = 0.f;
    int i = st;
    for (; i + 4 <= en; i += 4) {
        const int sn0 = ss[i], sn1 = ss[i + 1], sn2 = ss[i + 2], sn3 = ss[i + 3];
        const float4 q0 = ee4[i], q1 = ee4[i + 1], q2 = ee4[i + 2], q3 = ee4[i + 3];
        const unsigned int u0 = ((const unsigned int*)(fbase + (size_t)sn0 * 128))[lane];
        const unsigned int u1 = ((const unsigned int*)(fbase + (size_t)sn1 * 128))[lane];
        const unsigned int u2 = ((const unsigned int*)(fbase + (size_t)sn2 * 128))[lane];
        const unsigned int u3 = ((const unsigned int*)(fbase + (size_t)sn3 * 128))[lane];
        const float e0 = (h < 2) ? (h == 0 ? q0.x : q0.y) : (h == 2 ? q0.z : q0.w);
        const float e1 = (h < 2) ? (h == 0 ? q1.x : q1.y) : (h == 2 ? q1.z : q1.w);
        const float e2 = (h < 2) ? (h == 0 ? q2.x : q2.y) : (h == 2 ? q2.z : q2.w);
        const float e3 = (h < 2) ? (h == 0 ? q3.x : q3.y) : (h == 2 ? q3.z : q3.w);
        acc0 += e0 * bf_lo(u0) + e1 * bf_lo(u1) + e2 * bf_lo(u2) + e3 * bf_lo(u3);
        acc1 += e0 * bf_hi(u0) + e1 * bf_hi(u1) + e2 * bf_hi(u2) + e3 * bf_hi(u3);
        za += (e0 + e1) + (e2 + e3);
    }
    for (; i < en; ++i) {
        const int sn = ss[i];
        const float4 q = ee4[i];
        const unsigned int u = ((const unsigned int*)(fbase + (size_t)sn * 128))[lane];
        const float e = (h < 2) ? (h == 0 ? q.x : q.y) : (h == 2 ? q.z : q.w);
        acc0 += e * bf_lo(u);
        acc1 += e * bf_hi(u);
        za += e;
    }
    float v0 = 0.f, v1 = 0.f;
    if (en > st) { const float iz = 1.f / za; v0 = acc0 * iz; v1 = acc1 * iz; }
    v0 = v0 > 0.f ? v0 : (expf(v0) - 1.f);
    v1 = v1 > 0.f ? v1 : (expf(v1) - 1.f);
    zb[(size_t)(p * NN + n) * 64 + lane] =
        (unsigned int)f2bf(v0) | ((unsigned int)f2bf(v1) << 16);
}

// ---------------- K5: semantic scores (z bf16, already elu'd) ------------
__global__ __launch_bounds__(256) void k_sem_score(
    const unsigned int* __restrict__ zb, const float* __restrict__ w1,
    const float* __restrict__ b1, const float* __restrict__ w2,
    float* __restrict__ wsem)
{
    __shared__ float sZ[64 * 128];
    __shared__ float sPart[8];
    const int tid = threadIdx.x;
    const int p  = blockIdx.y;
    const int n0 = blockIdx.x * 64;

    float4* sZ4 = (float4*)sZ;
    for (int i = tid; i < 2048; i += 256) {
        const int row = i >> 5, c4 = i & 31;
        float4 v = make_float4(0.f, 0.f, 0.f, 0.f);
        if (n0 + row < NN) {
            const uint2 u = ((const uint2*)(zb + (size_t)(p * NN + n0 + row) * 64))[c4];
            v.x = bf_lo(u.x); v.y = bf_hi(u.x); v.z = bf_lo(u.y); v.w = bf_hi(u.y);
        }
        sZ4[i] = v;
    }
    __syncthreads();

    const int tc = tid & 31;
    const int tr = tid >> 5;
    const float4* w14 = (const float4*)w1;

    float4 acc[8];
    #pragma unroll
    for (int r = 0; r < 8; ++r) acc[r] = make_float4(0.f, 0.f, 0.f, 0.f);

    for (int kq = 0; kq < 32; ++kq) {
        const float4 wv0 = w14[(4 * kq + 0) * 32 + tc];
        const float4 wv1 = w14[(4 * kq + 1) * 32 + tc];
        const float4 wv2 = w14[(4 * kq + 2) * 32 + tc];
        const float4 wv3 = w14[(4 * kq + 3) * 32 + tc];
        #pragma unroll
        for (int r = 0; r < 8; ++r) {
            const float4 zv = sZ4[(tr * 8 + r) * 32 + kq];
            fma4(acc[r], zv.x, wv0);
            fma4(acc[r], zv.y, wv1);
            fma4(acc[r], zv.z, wv2);
            fma4(acc[r], zv.w, wv3);
        }
    }

    const float4 bb = ((const float4*)b1)[tc];
    const float4 ww = ((const float4*)w2)[tc];

    float local = 0.f;
    for (int r = 0; r < 8; ++r) {
        float pr = tanhf(acc[r].x + bb.x) * ww.x
                 + tanhf(acc[r].y + bb.y) * ww.y
                 + tanhf(acc[r].z + bb.z) * ww.z
                 + tanhf(acc[r].w + bb.w) * ww.w;
        pr += __shfl_xor(pr, 1);
        pr += __shfl_xor(pr, 2);
        pr += __shfl_xor(pr, 4);
        pr += __shfl_xor(pr, 8);
        pr += __shfl_xor(pr, 16);
        if (tc == 0 && (n0 + tr * 8 + r) < NN) local += pr;
    }
    if (tc == 0) sPart[tr] = local;
    __syncthreads();
    if (tid == 0) {
        float t = 0.f;
        for (int i = 0; i < 8; ++i) t += sPart[i];
        atomicAdd(&wsem[p], t);
    }
}

// ---------------- K6: bsem = softmax(wsem / N) ----------------
__global__ void k_bsem(const float* __restrict__ wsem, float* __restrict__ bsem)
{
    if (threadIdx.x == 0 && blockIdx.x == 0) {
        float w[PP];
        for (int p = 0; p < PP; ++p) w[p] = wsem[p] / (float)NN;
        float m = fmaxf(w[0], fmaxf(w[1], w[2]));
        float s = 0.f;
        for (int p = 0; p < PP; ++p) { w[p] = expf(w[p] - m); s += w[p]; }
        for (int p = 0; p < PP; ++p) bsem[p] = w[p] / s;
    }
}

// ---------------- K7: out = sum_p bsem[p] * z_p (z bf16, elu'd) ----------
__global__ __launch_bounds__(256) void k_final(
    const unsigned int* __restrict__ zb, const float* __restrict__ bsem,
    float* __restrict__ out)
{
    const int i = blockIdx.x * 256 + threadIdx.x;
    if (i >= NN * 64) return;
    const float b0 = bsem[0], b1 = bsem[1], b2 = bsem[2];
    const unsigned int u0 = zb[i];
    const unsigned int u1 = zb[(size_t)NN * 64 + i];
    const unsigned int u2 = zb[(size_t)2 * NN * 64 + i];
    float2 o;
    o.x = b0 * bf_lo(u0) + b1 * bf_lo(u1) + b2 * bf_lo(u2);
    o.y = b0 * bf_hi(u0) + b1 * bf_hi(u1) + b2 * bf_hi(u2);
    ((float2*)out)[i] = o;
}

extern "C" void kernel_launch(void* const* d_in, const int* in_sizes, int n_in,
                              void* d_out, int out_size, void* d_ws, size_t ws_size,
                              hipStream_t stream) {
    const float* h      = (const float*)d_in[0];
    const float* c      = (const float*)d_in[1];
    const float* fa_w1  = (const float*)d_in[2];
    const float* fa_b1  = (const float*)d_in[3];
    const float* fa_w2  = (const float*)d_in[4];
    const float* gat_W  = (const float*)d_in[5];
    const float* attn_l = (const float*)d_in[6];
    const float* attn_r = (const float*)d_in[7];
    const float* sa_w1  = (const float*)d_in[8];
    const float* sa_b1  = (const float*)d_in[9];
    const float* sa_w2  = (const float*)d_in[10];
    const int*   src    = (const int*)d_in[11];
    const int*   dst    = (const int*)d_in[12];
    float* out = (float*)d_out;

    float* ws = (float*)d_ws;
    float* x     = ws;                       // 6,400,000 f
    // x region is dead after k_gat_gemm; reuse for sorted edge arrays
    int*   s_src = (int*)ws;                 // 1,200,000 i (aliases x)
    float* s_ee  = ws + 1200000;             // 4,800,000 f (aliases x)
    unsigned short* featb = (unsigned short*)(ws + 7400000); // 19.2M bf16 = 9.6M f
    float* el    = ws + 17000000;            //    600,000 f
    float* er    = el + 600000;              //    600,000 f
    unsigned int* zb = (unsigned int*)(er + 600000); // 9,600,000 u32 (bf16 pairs)
    int*   row_start = (int*)(ws + 27800000); // 150,003 i
    int*   cursor    = row_start + 150003;   // 150,000 i
    int*   psum      = cursor + 150000;      // 588 i
    int*   deg       = psum + 588;           // 150,000 i
    float* wsem      = (float*)(deg + 150000); // 4 f
    float* bsem      = wsem + 4;             // 4 f

    hipMemsetAsync(deg, 0, (size_t)(150000 + 4) * sizeof(float), stream);

    k_fa<<<(NN + 3) / 4, 256, 0, stream>>>(h, c, fa_w1, fa_b1, fa_w2, x);
    k_gat_gemm<<<dim3((NN + 63) / 64, PP), 256, 0, stream>>>(x, gat_W, attn_l, attn_r, featb, el, er);
    k_hist<<<dim3((EE + 255) / 256, PP), 256, 0, stream>>>(dst, deg);
    k_partial<<<dim3(NBLK, PP), 256, 0, stream>>>(deg, psum);
    k_scanpsum<<<PP, 64, 0, stream>>>(psum);
    k_scanfinal<<<dim3(NBLK, PP), 256, 0, stream>>>(deg, psum, row_start, cursor);
    k_scatter<<<dim3((EE + 255) / 256, PP), 256, 0, stream>>>(src, dst, el, er, cursor, s_src, s_ee);
    k_agg<<<dim3((NN + 3) / 4, PP), 256, 0, stream>>>(row_start, s_src, s_ee, featb, zb);
    k_sem_score<<<dim3((NN + 63) / 64, PP), 256, 0, stream>>>(zb, sa_w1, sa_b1, sa_w2, wsem);
    k_bsem<<<1, 64, 0, stream>>>(wsem, bsem);
    k_final<<<(NN * 64 + 255) / 256, 256, 0, stream>>>(zb, bsem, out);
}